// Round 1
// baseline (824.838 us; speedup 1.0000x reference)
//
#include <hip/hip_runtime.h>

// GCN 2-layer forward on MI355X.
// Layout of math:
//   deg[i]   = 1 + in-degree(i)          (self-loops)
//   dinv[i]  = rsqrt(deg[i])
//   xws[i,:] = (x[i,:] @ W1) * dinv[i]                       [N,16]
//   h[i,:]   = relu(b1 + dinv[i] * (sum_{src->i} xws[src,:] + xws[i,:]))
//   hws[i,:] = (h[i,:] @ W2) * dinv[i]                       [N,32]
//   out[i,:] = b2 + dinv[i] * (sum_{src->i} hws[src,:] + hws[i,:])
// d_out = [out (N*32) | h (N*16)]

#define NN 100000
#define NE 3200000
#define FIN 512
#define HID 16
#define NCLS 32

// workspace float offsets
#define OFF_DEG  0              // NN         (becomes dinv in-place)
#define OFF_ACC1 (NN)           // NN*16
#define OFF_ACC2 (NN*17)        // NN*32
#define OFF_XWS  (NN*49)        // NN*16
#define OFF_HWS  (NN*65)        // NN*32
// total NN*97 floats = 38.8 MB

__global__ void k_init(float* __restrict__ ws) {
    // deg=1.0 (self loop), acc1=0, acc2=0 : contiguous NN*49 floats
    int i = blockIdx.x * blockDim.x + threadIdx.x;
    if (i < NN * 49) ws[i] = (i < NN) ? 1.0f : 0.0f;
}

__global__ void k_deg(const int* __restrict__ dst, float* __restrict__ deg) {
    int e = blockIdx.x * blockDim.x + threadIdx.x;
    if (e < NE) unsafeAtomicAdd(&deg[dst[e]], 1.0f);
}

__global__ void k_dinv(float* __restrict__ deg) {
    int i = blockIdx.x * blockDim.x + threadIdx.x;
    if (i < NN) deg[i] = rsqrtf(deg[i]);   // deg >= 1 always
}

// GEMM1: 16 nodes/block, 16 threads/node (one output column each).
// W1 transposed into LDS, padded row stride for float4 reads.
__global__ __launch_bounds__(256) void k_xw(const float* __restrict__ x,
                                            const float* __restrict__ W1,
                                            const float* __restrict__ dinv,
                                            float* __restrict__ xws) {
    __shared__ float w1t[HID][FIN + 4];  // +4 floats pad: keeps 16B align, breaks bank pattern
    for (int t = threadIdx.x; t < FIN * HID; t += 256) {
        int k = t >> 4, j = t & 15;
        w1t[j][k] = W1[t];
    }
    __syncthreads();
    int node = blockIdx.x * 16 + (threadIdx.x >> 4);
    int j = threadIdx.x & 15;
    const float4* xrow = reinterpret_cast<const float4*>(x + (size_t)node * FIN);
    const float4* wrow = reinterpret_cast<const float4*>(&w1t[j][0]);
    float acc = 0.f;
#pragma unroll 8
    for (int k4 = 0; k4 < FIN / 4; ++k4) {
        float4 xv = xrow[k4];
        float4 wv = wrow[k4];
        acc += xv.x * wv.x + xv.y * wv.y + xv.z * wv.z + xv.w * wv.w;
    }
    xws[node * HID + j] = acc * dinv[node];
}

// Edge scatter, layer 1: one thread per (edge, j<16)
__global__ void k_edge1(const int* __restrict__ src, const int* __restrict__ dst,
                        const float* __restrict__ xws, float* __restrict__ acc1) {
    int t = blockIdx.x * blockDim.x + threadIdx.x;
    if (t >= NE * HID) return;
    int e = t >> 4, j = t & 15;
    int s = src[e], d = dst[e];
    unsafeAtomicAdd(&acc1[d * HID + j], xws[s * HID + j]);
}

__global__ void k_h(const float* __restrict__ acc1, const float* __restrict__ xws,
                    const float* __restrict__ dinv, const float* __restrict__ b1,
                    float* __restrict__ hout) {
    int t = blockIdx.x * blockDim.x + threadIdx.x;
    if (t >= NN * HID) return;
    int i = t >> 4, j = t & 15;
    float v = b1[j] + dinv[i] * (acc1[t] + xws[t]);
    hout[t] = v > 0.f ? v : 0.f;
}

// GEMM2: thread per (node, jo<32); W2 in LDS; h rows broadcast via L1.
__global__ __launch_bounds__(256) void k_hw(const float* __restrict__ h,
                                            const float* __restrict__ W2,
                                            const float* __restrict__ dinv,
                                            float* __restrict__ hws) {
    __shared__ float w2[HID * NCLS];
    for (int t = threadIdx.x; t < HID * NCLS; t += 256) w2[t] = W2[t];
    __syncthreads();
    int t = blockIdx.x * blockDim.x + threadIdx.x;
    if (t >= NN * NCLS) return;
    int i = t >> 5, jo = t & 31;
    const float* hrow = h + i * HID;
    float acc = 0.f;
#pragma unroll
    for (int k = 0; k < HID; ++k) acc += hrow[k] * w2[k * NCLS + jo];
    hws[t] = acc * dinv[i];
}

// Edge scatter, layer 2: one thread per (edge, jo<32)
__global__ void k_edge2(const int* __restrict__ src, const int* __restrict__ dst,
                        const float* __restrict__ hws, float* __restrict__ acc2) {
    int t = blockIdx.x * blockDim.x + threadIdx.x;
    if (t >= NE * NCLS) return;
    int e = t >> 5, j = t & 31;
    int s = src[e], d = dst[e];
    unsafeAtomicAdd(&acc2[d * NCLS + j], hws[s * NCLS + j]);
}

__global__ void k_out(const float* __restrict__ acc2, const float* __restrict__ hws,
                      const float* __restrict__ dinv, const float* __restrict__ b2,
                      float* __restrict__ out) {
    int t = blockIdx.x * blockDim.x + threadIdx.x;
    if (t >= NN * NCLS) return;
    int i = t >> 5, jo = t & 31;
    out[t] = b2[jo] + dinv[i] * (acc2[t] + hws[t]);
}

extern "C" void kernel_launch(void* const* d_in, const int* in_sizes, int n_in,
                              void* d_out, int out_size, void* d_ws, size_t ws_size,
                              hipStream_t stream) {
    const float* x  = (const float*)d_in[0];
    const int* ei   = (const int*)d_in[1];      // [2][NE]
    const float* W1 = (const float*)d_in[2];
    const float* b1 = (const float*)d_in[3];
    const float* W2 = (const float*)d_in[4];
    const float* b2 = (const float*)d_in[5];

    const int* src = ei;
    const int* dst = ei + NE;

    float* ws   = (float*)d_ws;
    float* deg  = ws + OFF_DEG;    // then dinv
    float* acc1 = ws + OFF_ACC1;
    float* acc2 = ws + OFF_ACC2;
    float* xws  = ws + OFF_XWS;
    float* hws  = ws + OFF_HWS;

    float* outp = (float*)d_out;           // [NN*32]
    float* hout = outp + NN * NCLS;        // [NN*16]

    const int B = 256;
    hipLaunchKernelGGL(k_init,  dim3((NN * 49 + B - 1) / B), dim3(B), 0, stream, ws);
    hipLaunchKernelGGL(k_deg,   dim3((NE + B - 1) / B), dim3(B), 0, stream, dst, deg);
    hipLaunchKernelGGL(k_dinv,  dim3((NN + B - 1) / B), dim3(B), 0, stream, deg);
    hipLaunchKernelGGL(k_xw,    dim3(NN / 16), dim3(B), 0, stream, x, W1, deg, xws);
    hipLaunchKernelGGL(k_edge1, dim3((NE * HID + B - 1) / B), dim3(B), 0, stream, src, dst, xws, acc1);
    hipLaunchKernelGGL(k_h,     dim3((NN * HID + B - 1) / B), dim3(B), 0, stream, acc1, xws, deg, b1, hout);
    hipLaunchKernelGGL(k_hw,    dim3((NN * NCLS + B - 1) / B), dim3(B), 0, stream, hout, W2, deg, hws);
    hipLaunchKernelGGL(k_edge2, dim3((NE * NCLS + B - 1) / B), dim3(B), 0, stream, src, dst, hws, acc2);
    hipLaunchKernelGGL(k_out,   dim3((NN * NCLS + B - 1) / B), dim3(B), 0, stream, acc2, hws, deg, b2, outp);
}

// Round 2
// 753.717 us; speedup vs baseline: 1.0944x; 1.0944x over previous
//
#include <hip/hip_runtime.h>

// GCN 2-layer forward, CSR-gather formulation.
//   cnt[i]   = in-degree(i)            (excluding self-loop)
//   dinv[i]  = rsqrt(cnt[i] + 1)
//   CSR: start[] = exclusive scan of cnt; esrc[] = src ids sorted by dst
//   xws[i,:] = (x[i,:] @ W1) * dinv[i]                       [N,16]
//   h[i,:]   = relu(b1 + dinv[i] * (sum_{e: dst=i} xws[esrc[e],:] + xws[i,:]))
//   hws[i,:] = (h[i,:] @ W2) * dinv[i]                       [N,32]
//   out[i,:] = b2 + dinv[i] * (sum_{e: dst=i} hws[esrc[e],:] + hws[i,:])
// d_out = [out (N*32) | h (N*16)]

#define NN 100000
#define NE 3200000
#define FIN 512
#define HID 16
#define NCLS 32

// workspace element offsets (4-byte units)
#define OFF_CNT   0                      // int [NN]
#define OFF_START (NN)                   // int [NN]
#define OFF_POS   (2*NN)                 // int [NN]
#define OFF_DINV  (3*NN)                 // float [NN]
#define OFF_BSUM  (4*NN)                 // int [1024]
#define OFF_ESRC  (4*NN + 1024)          // int [NE]
#define OFF_XWS   (4*NN + 1024 + NE)     // float [NN*16]
#define OFF_HWS   (OFF_XWS + NN*16)      // float [NN*32]
// total = 52*NN + NE + 1024 elems ~= 33.6 MB

__global__ void k_zero(int* __restrict__ cnt) {
    int i = blockIdx.x * blockDim.x + threadIdx.x;
    if (i < NN) cnt[i] = 0;
}

__global__ void k_hist(const int* __restrict__ dst, int* __restrict__ cnt) {
    int e = blockIdx.x * blockDim.x + threadIdx.x;
    if (e < NE) atomicAdd(&cnt[dst[e]], 1);
}

// block-level exclusive scan, 256/block
__global__ __launch_bounds__(256) void k_scan1(const int* __restrict__ cnt,
                                               int* __restrict__ start,
                                               int* __restrict__ bsum) {
    __shared__ int s[256];
    int tid = threadIdx.x;
    int t = blockIdx.x * 256 + tid;
    int v = (t < NN) ? cnt[t] : 0;
    s[tid] = v;
    __syncthreads();
#pragma unroll
    for (int o = 1; o < 256; o <<= 1) {
        int u = (tid >= o) ? s[tid - o] : 0;
        __syncthreads();
        s[tid] += u;
        __syncthreads();
    }
    if (t < NN) start[t] = s[tid] - v;          // exclusive
    if (tid == 255) bsum[blockIdx.x] = s[255];  // block total
}

// scan the 391 block sums (single block of 512)
__global__ __launch_bounds__(512) void k_scan2(int* __restrict__ bsum, int nblk) {
    __shared__ int s[512];
    int tid = threadIdx.x;
    int v = (tid < nblk) ? bsum[tid] : 0;
    s[tid] = v;
    __syncthreads();
#pragma unroll
    for (int o = 1; o < 512; o <<= 1) {
        int u = (tid >= o) ? s[tid - o] : 0;
        __syncthreads();
        s[tid] += u;
        __syncthreads();
    }
    if (tid < nblk) bsum[tid] = s[tid] - v;     // exclusive, in-place
}

// add block offsets; init pos; compute dinv
__global__ __launch_bounds__(256) void k_scan3(const int* __restrict__ cnt,
                                               int* __restrict__ start,
                                               int* __restrict__ pos,
                                               float* __restrict__ dinv,
                                               const int* __restrict__ bsum) {
    int t = blockIdx.x * 256 + threadIdx.x;
    if (t >= NN) return;
    int st = start[t] + bsum[blockIdx.x];
    start[t] = st;
    pos[t] = st;
    dinv[t] = rsqrtf((float)(cnt[t] + 1));
}

__global__ void k_fill(const int* __restrict__ src, const int* __restrict__ dst,
                       int* __restrict__ pos, int* __restrict__ esrc) {
    int e = blockIdx.x * blockDim.x + threadIdx.x;
    if (e >= NE) return;
    int p = atomicAdd(&pos[dst[e]], 1);
    esrc[p] = src[e];
}

// GEMM1: 16 nodes/block, 16 threads/node (one output column each).
__global__ __launch_bounds__(256) void k_xw(const float* __restrict__ x,
                                            const float* __restrict__ W1,
                                            const float* __restrict__ dinv,
                                            float* __restrict__ xws) {
    __shared__ float w1t[HID][FIN + 4];
    for (int t = threadIdx.x; t < FIN * HID; t += 256) {
        int k = t >> 4, j = t & 15;
        w1t[j][k] = W1[t];
    }
    __syncthreads();
    int node = blockIdx.x * 16 + (threadIdx.x >> 4);
    int j = threadIdx.x & 15;
    const float4* xrow = reinterpret_cast<const float4*>(x + (size_t)node * FIN);
    const float4* wrow = reinterpret_cast<const float4*>(&w1t[j][0]);
    float acc = 0.f;
#pragma unroll 8
    for (int k4 = 0; k4 < FIN / 4; ++k4) {
        float4 xv = xrow[k4];
        float4 wv = wrow[k4];
        acc += xv.x * wv.x + xv.y * wv.y + xv.z * wv.z + xv.w * wv.w;
    }
    xws[node * HID + j] = acc * dinv[node];
}

// Gather layer 1: 16 lanes (features) x 4 edge-parallel per node, 4 nodes/wave? No:
// one node per 64-lane group would waste; use 4 nodes per wave:
// lane = tid & 63; subnode = (tid>>4)&3 ... simpler: 16 lanes per node, 4 edge-par via c.
// Mapping: node gets lanes [g*16..g*16+15] of its wave? That gives edge-par 1.
// Chosen: 1 node per wave, j = lane&15, c = lane>>4 (4-way edge parallel).
__global__ __launch_bounds__(256) void k_gather1(const int* __restrict__ start,
                                                 const int* __restrict__ cnt,
                                                 const int* __restrict__ esrc,
                                                 const float* __restrict__ xws,
                                                 const float* __restrict__ dinv,
                                                 const float* __restrict__ b1,
                                                 float* __restrict__ hout) {
    int wave = (blockIdx.x * 256 + threadIdx.x) >> 6;   // global wave id = node
    if (wave >= NN) return;
    int i = wave;
    int lane = threadIdx.x & 63;
    int j = lane & 15;
    int c = lane >> 4;                                   // 0..3
    int st = start[i], en = st + cnt[i];
    float sum = 0.f;
    for (int e = st + c; e < en; e += 4) {
        int s = esrc[e];
        sum += xws[s * HID + j];
    }
    sum += __shfl_xor(sum, 16);
    sum += __shfl_xor(sum, 32);
    if (c == 0) {
        float v = b1[j] + dinv[i] * (sum + xws[i * HID + j]);
        hout[i * HID + j] = v > 0.f ? v : 0.f;
    }
}

// GEMM2: thread per (node, jo<32); W2 in LDS.
__global__ __launch_bounds__(256) void k_hw(const float* __restrict__ h,
                                            const float* __restrict__ W2,
                                            const float* __restrict__ dinv,
                                            float* __restrict__ hws) {
    __shared__ float w2[HID * NCLS];
    for (int t = threadIdx.x; t < HID * NCLS; t += 256) w2[t] = W2[t];
    __syncthreads();
    int t = blockIdx.x * blockDim.x + threadIdx.x;
    if (t >= NN * NCLS) return;
    int i = t >> 5, jo = t & 31;
    const float* hrow = h + i * HID;
    float acc = 0.f;
#pragma unroll
    for (int k = 0; k < HID; ++k) acc += hrow[k] * w2[k * NCLS + jo];
    hws[t] = acc * dinv[i];
}

// Gather layer 2: one node per wave, j = lane&31, c = lane>>5 (2-way edge parallel).
__global__ __launch_bounds__(256) void k_gather2(const int* __restrict__ start,
                                                 const int* __restrict__ cnt,
                                                 const int* __restrict__ esrc,
                                                 const float* __restrict__ hws,
                                                 const float* __restrict__ dinv,
                                                 const float* __restrict__ b2,
                                                 float* __restrict__ out) {
    int wave = (blockIdx.x * 256 + threadIdx.x) >> 6;
    if (wave >= NN) return;
    int i = wave;
    int lane = threadIdx.x & 63;
    int j = lane & 31;
    int c = lane >> 5;                                   // 0..1
    int st = start[i], en = st + cnt[i];
    float sum = 0.f;
    for (int e = st + c; e < en; e += 2) {
        int s = esrc[e];
        sum += hws[s * NCLS + j];
    }
    sum += __shfl_xor(sum, 32);
    if (c == 0) {
        out[i * NCLS + j] = b2[j] + dinv[i] * (sum + hws[i * NCLS + j]);
    }
}

extern "C" void kernel_launch(void* const* d_in, const int* in_sizes, int n_in,
                              void* d_out, int out_size, void* d_ws, size_t ws_size,
                              hipStream_t stream) {
    const float* x  = (const float*)d_in[0];
    const int* ei   = (const int*)d_in[1];      // [2][NE]
    const float* W1 = (const float*)d_in[2];
    const float* b1 = (const float*)d_in[3];
    const float* W2 = (const float*)d_in[4];
    const float* b2 = (const float*)d_in[5];

    const int* src = ei;
    const int* dst = ei + NE;

    char* ws = (char*)d_ws;
    int*   cnt   = (int*)ws + OFF_CNT;
    int*   start = (int*)ws + OFF_START;
    int*   pos   = (int*)ws + OFF_POS;
    float* dinv  = (float*)ws + OFF_DINV;
    int*   bsum  = (int*)ws + OFF_BSUM;
    int*   esrc  = (int*)ws + OFF_ESRC;
    float* xws   = (float*)ws + OFF_XWS;
    float* hws   = (float*)ws + OFF_HWS;

    float* outp = (float*)d_out;           // [NN*32]
    float* hout = outp + NN * NCLS;        // [NN*16]

    const int B = 256;
    const int nscan = (NN + B - 1) / B;    // 391

    hipLaunchKernelGGL(k_zero,  dim3(nscan), dim3(B), 0, stream, cnt);
    hipLaunchKernelGGL(k_hist,  dim3((NE + B - 1) / B), dim3(B), 0, stream, dst, cnt);
    hipLaunchKernelGGL(k_scan1, dim3(nscan), dim3(B), 0, stream, cnt, start, bsum);
    hipLaunchKernelGGL(k_scan2, dim3(1), dim3(512), 0, stream, bsum, nscan);
    hipLaunchKernelGGL(k_scan3, dim3(nscan), dim3(B), 0, stream, cnt, start, pos, dinv, bsum);
    hipLaunchKernelGGL(k_fill,  dim3((NE + B - 1) / B), dim3(B), 0, stream, src, dst, pos, esrc);
    hipLaunchKernelGGL(k_xw,    dim3(NN / 16), dim3(B), 0, stream, x, W1, dinv, xws);
    hipLaunchKernelGGL(k_gather1, dim3((NN * 64 + B - 1) / B), dim3(B), 0, stream,
                       start, cnt, esrc, xws, dinv, b1, hout);
    hipLaunchKernelGGL(k_hw,    dim3((NN * NCLS + B - 1) / B), dim3(B), 0, stream, hout, W2, dinv, hws);
    hipLaunchKernelGGL(k_gather2, dim3((NN * 64 + B - 1) / B), dim3(B), 0, stream,
                       start, cnt, esrc, hws, dinv, b2, outp);
}

// Round 3
// 450.769 us; speedup vs baseline: 1.8298x; 1.6721x over previous
//
#include <hip/hip_runtime.h>

// GCN 2-layer forward, CSR-gather with hierarchical radix binning.
// Bucket = dst >> 8  (391 buckets x 256 nodes).
//   k_bhist: bucket histogram (LDS-aggregated)
//   k_bscan: bucket base offsets
//   k_binA : scatter packed records (src<<8 | dstLocal) into bucket regions
//   k_binB : per-bucket CSR build in LDS -> esrc (in-place), start, cnt, dinv
//   k_xw   : xws = (x @ W1) * dinv
//   k_gather1: h = relu(b1 + dinv*(sum xws[src] + xws[i]))
//   k_hw   : hws = (h @ W2) * dinv
//   k_gather2: out = b2 + dinv*(sum hws[src] + hws[i])
// d_out = [out (N*32) | h (N*16)]

#define NN 100000
#define NE 3200000
#define FIN 512
#define HID 16
#define NCLS 32
#define NB 391          // ceil(NN/256)
#define NBP 512         // padded bucket slots
#define CAP_B 9216      // max records per bucket (mean 8192, +11 sigma)

// workspace element offsets (4-byte units)
#define OFF_BCNT  0                     // int [NBP]
#define OFF_BBASE (NBP)                 // int [NBP]
#define OFF_BPOS  (2*NBP)               // int [NBP]
#define OFF_START (3*NBP)               // int [NN]
#define OFF_CNT   (3*NBP + NN)          // int [NN]
#define OFF_DINV  (3*NBP + 2*NN)        // float [NN]
#define OFF_EP    (3*NBP + 3*NN)        // u32 [NE] packed records; becomes esrc
#define OFF_XWS   (3*NBP + 3*NN + NE)   // float [NN*16]
#define OFF_HWS   (OFF_XWS + NN*16)     // float [NN*32]
// total = 3*512 + 51*NN + NE = 8,301,536 elems ~= 33.2 MB

__global__ __launch_bounds__(512) void k_zeroB(int* __restrict__ bcnt) {
    bcnt[threadIdx.x] = 0;
}

__global__ __launch_bounds__(256) void k_bhist(const int* __restrict__ dst,
                                               int* __restrict__ bcnt) {
    __shared__ int h[NBP];
    for (int t = threadIdx.x; t < NBP; t += 256) h[t] = 0;
    __syncthreads();
    int stride = gridDim.x * 256;
    for (int e = blockIdx.x * 256 + threadIdx.x; e < NE; e += stride)
        atomicAdd(&h[dst[e] >> 8], 1);
    __syncthreads();
    for (int t = threadIdx.x; t < NB; t += 256)
        if (h[t]) atomicAdd(&bcnt[t], h[t]);
}

__global__ __launch_bounds__(512) void k_bscan(const int* __restrict__ bcnt,
                                               int* __restrict__ bbase,
                                               int* __restrict__ bpos) {
    __shared__ int s[512];
    int tid = threadIdx.x;
    int v = (tid < NB) ? bcnt[tid] : 0;
    s[tid] = v;
    __syncthreads();
#pragma unroll
    for (int o = 1; o < 512; o <<= 1) {
        int u = (tid >= o) ? s[tid - o] : 0;
        __syncthreads();
        s[tid] += u;
        __syncthreads();
    }
    int ex = s[tid] - v;
    if (tid < NB) { bbase[tid] = ex; bpos[tid] = ex; }
}

// Bin edges into bucket regions. 512 thr/block, 16 edges/thread, 8192/block.
__global__ __launch_bounds__(512) void k_binA(const int* __restrict__ src,
                                              const int* __restrict__ dst,
                                              int* __restrict__ bpos,
                                              unsigned* __restrict__ ep) {
    __shared__ int hist[NBP];
    __shared__ int gpos[NBP];
    int tid = threadIdx.x;
    hist[tid] = 0;
    __syncthreads();
    int base = blockIdx.x * 8192;
    unsigned rec[16];
    int meta[16];                       // (p_local << 9) | bucket, or -1
#pragma unroll
    for (int k = 0; k < 16; ++k) {
        int e = base + tid + k * 512;
        if (e < NE) {
            int s = src[e], d = dst[e];
            int b = d >> 8;
            int p = atomicAdd(&hist[b], 1);
            rec[k] = ((unsigned)s << 8) | (unsigned)(d & 255);
            meta[k] = (p << 9) | b;
        } else meta[k] = -1;
    }
    __syncthreads();
    int v = hist[tid];
    if (v > 0) gpos[tid] = atomicAdd(&bpos[tid], v);
    __syncthreads();
#pragma unroll
    for (int k = 0; k < 16; ++k) {
        if (meta[k] >= 0) {
            int b = meta[k] & 511;
            int p = meta[k] >> 9;
            ep[gpos[b] + p] = rec[k];
        }
    }
}

// Per-bucket CSR build in LDS. Block b owns nodes [b*256, b*256+256).
__global__ __launch_bounds__(256) void k_binB(unsigned* __restrict__ ep,
                                              const int* __restrict__ bbase,
                                              const int* __restrict__ bcnt,
                                              int* __restrict__ startA,
                                              int* __restrict__ cntA,
                                              float* __restrict__ dinv) {
    __shared__ int nh[256];
    __shared__ int ns[256];
    __shared__ int np_[256];
    __shared__ int esL[CAP_B];
    int tid = threadIdx.x;
    int b = blockIdx.x;
    int gbase = bbase[b];
    int bc = bcnt[b];
    nh[tid] = 0;
    __syncthreads();
    for (int t = tid; t < bc; t += 256)
        atomicAdd(&nh[ep[gbase + t] & 255], 1);
    __syncthreads();
    int v = nh[tid];
    ns[tid] = v;
    __syncthreads();
#pragma unroll
    for (int o = 1; o < 256; o <<= 1) {
        int u = (tid >= o) ? ns[tid - o] : 0;
        __syncthreads();
        ns[tid] += u;
        __syncthreads();
    }
    int ex = ns[tid] - v;               // exclusive start within bucket
    ns[tid] = ex;
    np_[tid] = ex;
    __syncthreads();
    for (int t = tid; t < bc; t += 256) {
        unsigned r = ep[gbase + t];
        int dl = r & 255;
        int p = atomicAdd(&np_[dl], 1);
        esL[p] = (int)(r >> 8);
    }
    __syncthreads();
    for (int t = tid; t < bc; t += 256)
        ep[gbase + t] = (unsigned)esL[t];   // in-place: ep becomes esrc
    int node = b * 256 + tid;
    if (node < NN) {
        startA[node] = gbase + ex;
        cntA[node]   = v;
        dinv[node]   = rsqrtf((float)(v + 1));
    }
}

// GEMM1: 16 nodes/block, 16 threads/node.
__global__ __launch_bounds__(256) void k_xw(const float* __restrict__ x,
                                            const float* __restrict__ W1,
                                            const float* __restrict__ dinv,
                                            float* __restrict__ xws) {
    __shared__ float w1t[HID][FIN + 4];
    for (int t = threadIdx.x; t < FIN * HID; t += 256) {
        int k = t >> 4, j = t & 15;
        w1t[j][k] = W1[t];
    }
    __syncthreads();
    int node = blockIdx.x * 16 + (threadIdx.x >> 4);
    int j = threadIdx.x & 15;
    const float4* xrow = reinterpret_cast<const float4*>(x + (size_t)node * FIN);
    const float4* wrow = reinterpret_cast<const float4*>(&w1t[j][0]);
    float acc = 0.f;
#pragma unroll 8
    for (int k4 = 0; k4 < FIN / 4; ++k4) {
        float4 xv = xrow[k4];
        float4 wv = wrow[k4];
        acc += xv.x * wv.x + xv.y * wv.y + xv.z * wv.z + xv.w * wv.w;
    }
    xws[node * HID + j] = acc * dinv[node];
}

// Gather layer 1: 1 node/wave, j = lane&15, 4-way edge parallel.
__global__ __launch_bounds__(256) void k_gather1(const int* __restrict__ startA,
                                                 const int* __restrict__ cntA,
                                                 const int* __restrict__ esrc,
                                                 const float* __restrict__ xws,
                                                 const float* __restrict__ dinv,
                                                 const float* __restrict__ b1,
                                                 float* __restrict__ hout) {
    int wave = (blockIdx.x * 256 + threadIdx.x) >> 6;
    if (wave >= NN) return;
    int i = wave;
    int lane = threadIdx.x & 63;
    int j = lane & 15;
    int c = lane >> 4;
    int st = startA[i], en = st + cntA[i];
    float sum = 0.f;
    for (int e = st + c; e < en; e += 4)
        sum += xws[esrc[e] * HID + j];
    sum += __shfl_xor(sum, 16);
    sum += __shfl_xor(sum, 32);
    if (c == 0) {
        float v = b1[j] + dinv[i] * (sum + xws[i * HID + j]);
        hout[i * HID + j] = v > 0.f ? v : 0.f;
    }
}

// GEMM2: thread per (node, jo<32); W2 in LDS.
__global__ __launch_bounds__(256) void k_hw(const float* __restrict__ h,
                                            const float* __restrict__ W2,
                                            const float* __restrict__ dinv,
                                            float* __restrict__ hws) {
    __shared__ float w2[HID * NCLS];
    for (int t = threadIdx.x; t < HID * NCLS; t += 256) w2[t] = W2[t];
    __syncthreads();
    int t = blockIdx.x * blockDim.x + threadIdx.x;
    if (t >= NN * NCLS) return;
    int i = t >> 5, jo = t & 31;
    const float* hrow = h + i * HID;
    float acc = 0.f;
#pragma unroll
    for (int k = 0; k < HID; ++k) acc += hrow[k] * w2[k * NCLS + jo];
    hws[t] = acc * dinv[i];
}

// Gather layer 2: 1 node/wave, j = lane&31, 2-way edge parallel.
__global__ __launch_bounds__(256) void k_gather2(const int* __restrict__ startA,
                                                 const int* __restrict__ cntA,
                                                 const int* __restrict__ esrc,
                                                 const float* __restrict__ hws,
                                                 const float* __restrict__ dinv,
                                                 const float* __restrict__ b2,
                                                 float* __restrict__ out) {
    int wave = (blockIdx.x * 256 + threadIdx.x) >> 6;
    if (wave >= NN) return;
    int i = wave;
    int lane = threadIdx.x & 63;
    int j = lane & 31;
    int c = lane >> 5;
    int st = startA[i], en = st + cntA[i];
    float sum = 0.f;
    for (int e = st + c; e < en; e += 2)
        sum += hws[esrc[e] * NCLS + j];
    sum += __shfl_xor(sum, 32);
    if (c == 0)
        out[i * NCLS + j] = b2[j] + dinv[i] * (sum + hws[i * NCLS + j]);
}

extern "C" void kernel_launch(void* const* d_in, const int* in_sizes, int n_in,
                              void* d_out, int out_size, void* d_ws, size_t ws_size,
                              hipStream_t stream) {
    const float* x  = (const float*)d_in[0];
    const int* ei   = (const int*)d_in[1];      // [2][NE]
    const float* W1 = (const float*)d_in[2];
    const float* b1 = (const float*)d_in[3];
    const float* W2 = (const float*)d_in[4];
    const float* b2 = (const float*)d_in[5];

    const int* src = ei;
    const int* dst = ei + NE;

    int* wsi = (int*)d_ws;
    int*      bcnt  = wsi + OFF_BCNT;
    int*      bbase = wsi + OFF_BBASE;
    int*      bpos  = wsi + OFF_BPOS;
    int*      startA= wsi + OFF_START;
    int*      cntA  = wsi + OFF_CNT;
    float*    dinv  = (float*)(wsi + OFF_DINV);
    unsigned* ep    = (unsigned*)(wsi + OFF_EP);   // packed, then esrc
    float*    xws   = (float*)(wsi + OFF_XWS);
    float*    hws   = (float*)(wsi + OFF_HWS);

    float* outp = (float*)d_out;           // [NN*32]
    float* hout = outp + NN * NCLS;        // [NN*16]

    const int B = 256;

    hipLaunchKernelGGL(k_zeroB, dim3(1), dim3(512), 0, stream, bcnt);
    hipLaunchKernelGGL(k_bhist, dim3(512), dim3(B), 0, stream, dst, bcnt);
    hipLaunchKernelGGL(k_bscan, dim3(1), dim3(512), 0, stream, bcnt, bbase, bpos);
    hipLaunchKernelGGL(k_binA,  dim3((NE + 8191) / 8192), dim3(512), 0, stream, src, dst, bpos, ep);
    hipLaunchKernelGGL(k_binB,  dim3(NB), dim3(B), 0, stream, ep, bbase, bcnt, startA, cntA, dinv);
    hipLaunchKernelGGL(k_xw,    dim3(NN / 16), dim3(B), 0, stream, x, W1, dinv, xws);
    hipLaunchKernelGGL(k_gather1, dim3((NN * 64 + B - 1) / B), dim3(B), 0, stream,
                       startA, cntA, (const int*)ep, xws, dinv, b1, hout);
    hipLaunchKernelGGL(k_hw,    dim3((NN * NCLS + B - 1) / B), dim3(B), 0, stream, hout, W2, dinv, hws);
    hipLaunchKernelGGL(k_gather2, dim3((NN * 64 + B - 1) / B), dim3(B), 0, stream,
                       startA, cntA, (const int*)ep, hws, dinv, b2, outp);
}

// Round 4
// 432.251 us; speedup vs baseline: 1.9082x; 1.0428x over previous
//
#include <hip/hip_runtime.h>

// GCN 2-layer forward, CSR-gather with hierarchical radix binning.
// Bucket = dst >> 8  (391 buckets x 256 nodes).
//   k_bhist: bucket histogram (LDS-aggregated)
//   k_bscan: bucket base offsets
//   k_binA : scatter packed records (src<<8 | dstLocal) into bucket regions
//   k_binB : per-bucket CSR build in LDS -> esrc (in-place), start, cnt, dinv
//   k_xw   : xws = (x @ W1) * dinv    [reg-accum, k-split x4 per node]
//   k_gather1: h = relu(b1 + dinv*(sum xws[src] + xws[i]))
//   k_hw   : hws = (h @ W2) * dinv
//   k_gather2: out = b2 + dinv*(sum hws[src] + hws[i])
// d_out = [out (N*32) | h (N*16)]

#define NN 100000
#define NE 3200000
#define FIN 512
#define HID 16
#define NCLS 32
#define NB 391          // ceil(NN/256)
#define NBP 512         // padded bucket slots
#define CAP_B 9216      // max records per bucket (mean 8192, +11 sigma)

// workspace element offsets (4-byte units)
#define OFF_BCNT  0                     // int [NBP]
#define OFF_BBASE (NBP)                 // int [NBP]
#define OFF_BPOS  (2*NBP)               // int [NBP]
#define OFF_START (3*NBP)               // int [NN]
#define OFF_CNT   (3*NBP + NN)          // int [NN]
#define OFF_DINV  (3*NBP + 2*NN)        // float [NN]
#define OFF_EP    (3*NBP + 3*NN)        // u32 [NE] packed records; becomes esrc
#define OFF_XWS   (3*NBP + 3*NN + NE)   // float [NN*16]
#define OFF_HWS   (OFF_XWS + NN*16)     // float [NN*32]

__global__ __launch_bounds__(512) void k_zeroB(int* __restrict__ bcnt) {
    bcnt[threadIdx.x] = 0;
}

__global__ __launch_bounds__(256) void k_bhist(const int* __restrict__ dst,
                                               int* __restrict__ bcnt) {
    __shared__ int h[NBP];
    for (int t = threadIdx.x; t < NBP; t += 256) h[t] = 0;
    __syncthreads();
    int stride = gridDim.x * 256;
    for (int e = blockIdx.x * 256 + threadIdx.x; e < NE; e += stride)
        atomicAdd(&h[dst[e] >> 8], 1);
    __syncthreads();
    for (int t = threadIdx.x; t < NB; t += 256)
        if (h[t]) atomicAdd(&bcnt[t], h[t]);
}

__global__ __launch_bounds__(512) void k_bscan(const int* __restrict__ bcnt,
                                               int* __restrict__ bbase,
                                               int* __restrict__ bpos) {
    __shared__ int s[512];
    int tid = threadIdx.x;
    int v = (tid < NB) ? bcnt[tid] : 0;
    s[tid] = v;
    __syncthreads();
#pragma unroll
    for (int o = 1; o < 512; o <<= 1) {
        int u = (tid >= o) ? s[tid - o] : 0;
        __syncthreads();
        s[tid] += u;
        __syncthreads();
    }
    int ex = s[tid] - v;
    if (tid < NB) { bbase[tid] = ex; bpos[tid] = ex; }
}

// Bin edges into bucket regions. 512 thr/block, 16 edges/thread, 8192/block.
__global__ __launch_bounds__(512) void k_binA(const int* __restrict__ src,
                                              const int* __restrict__ dst,
                                              int* __restrict__ bpos,
                                              unsigned* __restrict__ ep) {
    __shared__ int hist[NBP];
    __shared__ int gpos[NBP];
    int tid = threadIdx.x;
    hist[tid] = 0;
    __syncthreads();
    int base = blockIdx.x * 8192;
    unsigned rec[16];
    int meta[16];                       // (p_local << 9) | bucket, or -1
#pragma unroll
    for (int k = 0; k < 16; ++k) {
        int e = base + tid + k * 512;
        if (e < NE) {
            int s = src[e], d = dst[e];
            int b = d >> 8;
            int p = atomicAdd(&hist[b], 1);
            rec[k] = ((unsigned)s << 8) | (unsigned)(d & 255);
            meta[k] = (p << 9) | b;
        } else meta[k] = -1;
    }
    __syncthreads();
    int v = hist[tid];
    if (v > 0) gpos[tid] = atomicAdd(&bpos[tid], v);
    __syncthreads();
#pragma unroll
    for (int k = 0; k < 16; ++k) {
        if (meta[k] >= 0) {
            int b = meta[k] & 511;
            int p = meta[k] >> 9;
            ep[gpos[b] + p] = rec[k];
        }
    }
}

// Per-bucket CSR build in LDS. Block b owns nodes [b*256, b*256+256).
__global__ __launch_bounds__(256) void k_binB(unsigned* __restrict__ ep,
                                              const int* __restrict__ bbase,
                                              const int* __restrict__ bcnt,
                                              int* __restrict__ startA,
                                              int* __restrict__ cntA,
                                              float* __restrict__ dinv) {
    __shared__ int nh[256];
    __shared__ int ns[256];
    __shared__ int np_[256];
    __shared__ int esL[CAP_B];
    int tid = threadIdx.x;
    int b = blockIdx.x;
    int gbase = bbase[b];
    int bc = bcnt[b];
    nh[tid] = 0;
    __syncthreads();
    for (int t = tid; t < bc; t += 256)
        atomicAdd(&nh[ep[gbase + t] & 255], 1);
    __syncthreads();
    int v = nh[tid];
    ns[tid] = v;
    __syncthreads();
#pragma unroll
    for (int o = 1; o < 256; o <<= 1) {
        int u = (tid >= o) ? ns[tid - o] : 0;
        __syncthreads();
        ns[tid] += u;
        __syncthreads();
    }
    int ex = ns[tid] - v;               // exclusive start within bucket
    np_[tid] = ex;
    __syncthreads();
    for (int t = tid; t < bc; t += 256) {
        unsigned r = ep[gbase + t];
        int dl = r & 255;
        int p = atomicAdd(&np_[dl], 1);
        esL[p] = (int)(r >> 8);
    }
    __syncthreads();
    for (int t = tid; t < bc; t += 256)
        ep[gbase + t] = (unsigned)esL[t];   // in-place: ep becomes esrc
    int node = b * 256 + tid;
    if (node < NN) {
        startA[node] = gbase + ex;
        cntA[node]   = v;
        dinv[node]   = rsqrtf((float)(v + 1));
    }
}

// GEMM1: node = gt>>2, k-split c = gt&3. acc[16] in registers.
// Coalesced x reads (4 lanes cover 64B per node, contiguous over wave).
// W1 (32 KB) in LDS, read as near-uniform b128 broadcasts.
__global__ __launch_bounds__(256) void k_xw(const float* __restrict__ x,
                                            const float* __restrict__ W1,
                                            const float* __restrict__ dinv,
                                            float* __restrict__ xws) {
    __shared__ float w1[FIN * HID];     // 32 KB, row-major [k][j]
    for (int t = threadIdx.x; t < FIN * HID; t += 256) w1[t] = W1[t];
    __syncthreads();
    int gt = blockIdx.x * 256 + threadIdx.x;
    int node = gt >> 2;
    int c = gt & 3;
    bool valid = node < NN;
    const float4* xrow = reinterpret_cast<const float4*>(
        x + (valid ? (size_t)node * FIN : 0));
    float acc[HID];
#pragma unroll
    for (int j = 0; j < HID; ++j) acc[j] = 0.f;
#pragma unroll 4
    for (int q = c; q < FIN / 4; q += 4) {          // 32 quads per thread
        float4 xv = xrow[q];
        const float4* wv = reinterpret_cast<const float4*>(&w1[q * 4 * HID]);
#pragma unroll
        for (int e = 0; e < 4; ++e) {
            float xe = (e == 0) ? xv.x : (e == 1) ? xv.y : (e == 2) ? xv.z : xv.w;
#pragma unroll
            for (int j4 = 0; j4 < 4; ++j4) {
                float4 w4 = wv[e * 4 + j4];
                acc[j4 * 4 + 0] += xe * w4.x;
                acc[j4 * 4 + 1] += xe * w4.y;
                acc[j4 * 4 + 2] += xe * w4.z;
                acc[j4 * 4 + 3] += xe * w4.w;
            }
        }
    }
#pragma unroll
    for (int j = 0; j < HID; ++j) {
        acc[j] += __shfl_xor(acc[j], 1);
        acc[j] += __shfl_xor(acc[j], 2);
    }
    if (valid && c == 0) {
        float dv = dinv[node];
        float4* orow = reinterpret_cast<float4*>(xws + (size_t)node * HID);
#pragma unroll
        for (int j4 = 0; j4 < 4; ++j4)
            orow[j4] = make_float4(acc[j4 * 4 + 0] * dv, acc[j4 * 4 + 1] * dv,
                                   acc[j4 * 4 + 2] * dv, acc[j4 * 4 + 3] * dv);
    }
}

// Gather layer 1: 1 node/wave, j = lane&15, 4-way edge parallel.
__global__ __launch_bounds__(256) void k_gather1(const int* __restrict__ startA,
                                                 const int* __restrict__ cntA,
                                                 const int* __restrict__ esrc,
                                                 const float* __restrict__ xws,
                                                 const float* __restrict__ dinv,
                                                 const float* __restrict__ b1,
                                                 float* __restrict__ hout) {
    int wave = (blockIdx.x * 256 + threadIdx.x) >> 6;
    if (wave >= NN) return;
    int i = wave;
    int lane = threadIdx.x & 63;
    int j = lane & 15;
    int c = lane >> 4;
    int st = startA[i], en = st + cntA[i];
    float sum = 0.f;
    for (int e = st + c; e < en; e += 4)
        sum += xws[esrc[e] * HID + j];
    sum += __shfl_xor(sum, 16);
    sum += __shfl_xor(sum, 32);
    if (c == 0) {
        float v = b1[j] + dinv[i] * (sum + xws[i * HID + j]);
        hout[i * HID + j] = v > 0.f ? v : 0.f;
    }
}

// GEMM2: thread per (node, jo<32); W2 in LDS.
__global__ __launch_bounds__(256) void k_hw(const float* __restrict__ h,
                                            const float* __restrict__ W2,
                                            const float* __restrict__ dinv,
                                            float* __restrict__ hws) {
    __shared__ float w2[HID * NCLS];
    for (int t = threadIdx.x; t < HID * NCLS; t += 256) w2[t] = W2[t];
    __syncthreads();
    int t = blockIdx.x * blockDim.x + threadIdx.x;
    if (t >= NN * NCLS) return;
    int i = t >> 5, jo = t & 31;
    const float* hrow = h + i * HID;
    float acc = 0.f;
#pragma unroll
    for (int k = 0; k < HID; ++k) acc += hrow[k] * w2[k * NCLS + jo];
    hws[t] = acc * dinv[i];
}

// Gather layer 2: 1 node/wave, j = lane&31, 2-way edge parallel.
__global__ __launch_bounds__(256) void k_gather2(const int* __restrict__ startA,
                                                 const int* __restrict__ cntA,
                                                 const int* __restrict__ esrc,
                                                 const float* __restrict__ hws,
                                                 const float* __restrict__ dinv,
                                                 const float* __restrict__ b2,
                                                 float* __restrict__ out) {
    int wave = (blockIdx.x * 256 + threadIdx.x) >> 6;
    if (wave >= NN) return;
    int i = wave;
    int lane = threadIdx.x & 63;
    int j = lane & 31;
    int c = lane >> 5;
    int st = startA[i], en = st + cntA[i];
    float sum = 0.f;
    for (int e = st + c; e < en; e += 2)
        sum += hws[esrc[e] * NCLS + j];
    sum += __shfl_xor(sum, 32);
    if (c == 0)
        out[i * NCLS + j] = b2[j] + dinv[i] * (sum + hws[i * NCLS + j]);
}

extern "C" void kernel_launch(void* const* d_in, const int* in_sizes, int n_in,
                              void* d_out, int out_size, void* d_ws, size_t ws_size,
                              hipStream_t stream) {
    const float* x  = (const float*)d_in[0];
    const int* ei   = (const int*)d_in[1];      // [2][NE]
    const float* W1 = (const float*)d_in[2];
    const float* b1 = (const float*)d_in[3];
    const float* W2 = (const float*)d_in[4];
    const float* b2 = (const float*)d_in[5];

    const int* src = ei;
    const int* dst = ei + NE;

    int* wsi = (int*)d_ws;
    int*      bcnt  = wsi + OFF_BCNT;
    int*      bbase = wsi + OFF_BBASE;
    int*      bpos  = wsi + OFF_BPOS;
    int*      startA= wsi + OFF_START;
    int*      cntA  = wsi + OFF_CNT;
    float*    dinv  = (float*)(wsi + OFF_DINV);
    unsigned* ep    = (unsigned*)(wsi + OFF_EP);   // packed, then esrc
    float*    xws   = (float*)(wsi + OFF_XWS);
    float*    hws   = (float*)(wsi + OFF_HWS);

    float* outp = (float*)d_out;           // [NN*32]
    float* hout = outp + NN * NCLS;        // [NN*16]

    const int B = 256;

    hipLaunchKernelGGL(k_zeroB, dim3(1), dim3(512), 0, stream, bcnt);
    hipLaunchKernelGGL(k_bhist, dim3(512), dim3(B), 0, stream, dst, bcnt);
    hipLaunchKernelGGL(k_bscan, dim3(1), dim3(512), 0, stream, bcnt, bbase, bpos);
    hipLaunchKernelGGL(k_binA,  dim3((NE + 8191) / 8192), dim3(512), 0, stream, src, dst, bpos, ep);
    hipLaunchKernelGGL(k_binB,  dim3(NB), dim3(B), 0, stream, ep, bbase, bcnt, startA, cntA, dinv);
    hipLaunchKernelGGL(k_xw,    dim3((NN * 4 + B - 1) / B), dim3(B), 0, stream, x, W1, dinv, xws);
    hipLaunchKernelGGL(k_gather1, dim3((NN * 64 + B - 1) / B), dim3(B), 0, stream,
                       startA, cntA, (const int*)ep, xws, dinv, b1, hout);
    hipLaunchKernelGGL(k_hw,    dim3((NN * NCLS + B - 1) / B), dim3(B), 0, stream, hout, W2, dinv, hws);
    hipLaunchKernelGGL(k_gather2, dim3((NN * 64 + B - 1) / B), dim3(B), 0, stream,
                       startA, cntA, (const int*)ep, hws, dinv, b2, outp);
}

// Round 5
// 324.086 us; speedup vs baseline: 2.5451x; 1.3338x over previous
//
#include <hip/hip_runtime.h>

// GCN 2-layer forward, CSR-gather with hierarchical radix binning.
// Bucket = dst >> 8  (391 buckets x 256 nodes).
//   k_bhist: bucket histogram (LDS-aggregated)
//   k_bscan: bucket base offsets
//   k_binA : scatter packed records (src<<8 | dstLocal) into bucket regions
//   k_binB : per-bucket CSR build in LDS -> esrc (in-place), start, cnt, dinv
//   k_xw   : xws = (x @ W1) * dinv    [reg-accum, k-split x4 per node]
//   k_gather1: h = relu(b1 + dinv*(sum xws[src] + xws[i]))   [MLP-4 unrolled]
//   k_hw   : hws = (h @ W2) * dinv
//   k_gather2: out = b2 + dinv*(sum hws[src] + hws[i])       [MLP-4 unrolled]
// d_out = [out (N*32) | h (N*16)]

#define NN 100000
#define NE 3200000
#define FIN 512
#define HID 16
#define NCLS 32
#define NB 391          // ceil(NN/256)
#define NBP 512         // padded bucket slots
#define CAP_B 9216      // max records per bucket (mean 8192, +11 sigma)

// workspace element offsets (4-byte units)
#define OFF_BCNT  0                     // int [NBP]
#define OFF_BBASE (NBP)                 // int [NBP]
#define OFF_BPOS  (2*NBP)               // int [NBP]
#define OFF_START (3*NBP)               // int [NN]
#define OFF_CNT   (3*NBP + NN)          // int [NN]
#define OFF_DINV  (3*NBP + 2*NN)        // float [NN]
#define OFF_EP    (3*NBP + 3*NN)        // u32 [NE] packed records; becomes esrc
#define OFF_XWS   (3*NBP + 3*NN + NE)   // float [NN*16]
#define OFF_HWS   (OFF_XWS + NN*16)     // float [NN*32]

__global__ __launch_bounds__(512) void k_zeroB(int* __restrict__ bcnt) {
    bcnt[threadIdx.x] = 0;
}

__global__ __launch_bounds__(256) void k_bhist(const int* __restrict__ dst,
                                               int* __restrict__ bcnt) {
    __shared__ int h[NBP];
    for (int t = threadIdx.x; t < NBP; t += 256) h[t] = 0;
    __syncthreads();
    int stride = gridDim.x * 256;
    for (int e = blockIdx.x * 256 + threadIdx.x; e < NE; e += stride)
        atomicAdd(&h[dst[e] >> 8], 1);
    __syncthreads();
    for (int t = threadIdx.x; t < NB; t += 256)
        if (h[t]) atomicAdd(&bcnt[t], h[t]);
}

__global__ __launch_bounds__(512) void k_bscan(const int* __restrict__ bcnt,
                                               int* __restrict__ bbase,
                                               int* __restrict__ bpos) {
    __shared__ int s[512];
    int tid = threadIdx.x;
    int v = (tid < NB) ? bcnt[tid] : 0;
    s[tid] = v;
    __syncthreads();
#pragma unroll
    for (int o = 1; o < 512; o <<= 1) {
        int u = (tid >= o) ? s[tid - o] : 0;
        __syncthreads();
        s[tid] += u;
        __syncthreads();
    }
    int ex = s[tid] - v;
    if (tid < NB) { bbase[tid] = ex; bpos[tid] = ex; }
}

// Bin edges into bucket regions. 512 thr/block, 16 edges/thread, 8192/block.
__global__ __launch_bounds__(512) void k_binA(const int* __restrict__ src,
                                              const int* __restrict__ dst,
                                              int* __restrict__ bpos,
                                              unsigned* __restrict__ ep) {
    __shared__ int hist[NBP];
    __shared__ int gpos[NBP];
    int tid = threadIdx.x;
    hist[tid] = 0;
    __syncthreads();
    int base = blockIdx.x * 8192;
    unsigned rec[16];
    int meta[16];                       // (p_local << 9) | bucket, or -1
#pragma unroll
    for (int k = 0; k < 16; ++k) {
        int e = base + tid + k * 512;
        if (e < NE) {
            int s = src[e], d = dst[e];
            int b = d >> 8;
            int p = atomicAdd(&hist[b], 1);
            rec[k] = ((unsigned)s << 8) | (unsigned)(d & 255);
            meta[k] = (p << 9) | b;
        } else meta[k] = -1;
    }
    __syncthreads();
    int v = hist[tid];
    if (v > 0) gpos[tid] = atomicAdd(&bpos[tid], v);
    __syncthreads();
#pragma unroll
    for (int k = 0; k < 16; ++k) {
        if (meta[k] >= 0) {
            int b = meta[k] & 511;
            int p = meta[k] >> 9;
            ep[gpos[b] + p] = rec[k];
        }
    }
}

// Per-bucket CSR build in LDS. Block b owns nodes [b*256, b*256+256).
__global__ __launch_bounds__(256) void k_binB(unsigned* __restrict__ ep,
                                              const int* __restrict__ bbase,
                                              const int* __restrict__ bcnt,
                                              int* __restrict__ startA,
                                              int* __restrict__ cntA,
                                              float* __restrict__ dinv) {
    __shared__ int nh[256];
    __shared__ int ns[256];
    __shared__ int np_[256];
    __shared__ int esL[CAP_B];
    int tid = threadIdx.x;
    int b = blockIdx.x;
    int gbase = bbase[b];
    int bc = bcnt[b];
    nh[tid] = 0;
    __syncthreads();
    for (int t = tid; t < bc; t += 256)
        atomicAdd(&nh[ep[gbase + t] & 255], 1);
    __syncthreads();
    int v = nh[tid];
    ns[tid] = v;
    __syncthreads();
#pragma unroll
    for (int o = 1; o < 256; o <<= 1) {
        int u = (tid >= o) ? ns[tid - o] : 0;
        __syncthreads();
        ns[tid] += u;
        __syncthreads();
    }
    int ex = ns[tid] - v;               // exclusive start within bucket
    np_[tid] = ex;
    __syncthreads();
    for (int t = tid; t < bc; t += 256) {
        unsigned r = ep[gbase + t];
        int dl = r & 255;
        int p = atomicAdd(&np_[dl], 1);
        esL[p] = (int)(r >> 8);
    }
    __syncthreads();
    for (int t = tid; t < bc; t += 256)
        ep[gbase + t] = (unsigned)esL[t];   // in-place: ep becomes esrc
    int node = b * 256 + tid;
    if (node < NN) {
        startA[node] = gbase + ex;
        cntA[node]   = v;
        dinv[node]   = rsqrtf((float)(v + 1));
    }
}

// GEMM1: node = gt>>2, k-split c = gt&3. acc[16] in registers.
__global__ __launch_bounds__(256) void k_xw(const float* __restrict__ x,
                                            const float* __restrict__ W1,
                                            const float* __restrict__ dinv,
                                            float* __restrict__ xws) {
    __shared__ float w1[FIN * HID];     // 32 KB, row-major [k][j]
    for (int t = threadIdx.x; t < FIN * HID; t += 256) w1[t] = W1[t];
    __syncthreads();
    int gt = blockIdx.x * 256 + threadIdx.x;
    int node = gt >> 2;
    int c = gt & 3;
    bool valid = node < NN;
    const float4* xrow = reinterpret_cast<const float4*>(
        x + (valid ? (size_t)node * FIN : 0));
    float acc[HID];
#pragma unroll
    for (int j = 0; j < HID; ++j) acc[j] = 0.f;
#pragma unroll 4
    for (int q = c; q < FIN / 4; q += 4) {          // 32 quads per thread
        float4 xv = xrow[q];
        const float4* wv = reinterpret_cast<const float4*>(&w1[q * 4 * HID]);
#pragma unroll
        for (int e = 0; e < 4; ++e) {
            float xe = (e == 0) ? xv.x : (e == 1) ? xv.y : (e == 2) ? xv.z : xv.w;
#pragma unroll
            for (int j4 = 0; j4 < 4; ++j4) {
                float4 w4 = wv[e * 4 + j4];
                acc[j4 * 4 + 0] += xe * w4.x;
                acc[j4 * 4 + 1] += xe * w4.y;
                acc[j4 * 4 + 2] += xe * w4.z;
                acc[j4 * 4 + 3] += xe * w4.w;
            }
        }
    }
#pragma unroll
    for (int j = 0; j < HID; ++j) {
        acc[j] += __shfl_xor(acc[j], 1);
        acc[j] += __shfl_xor(acc[j], 2);
    }
    if (valid && c == 0) {
        float dv = dinv[node];
        float4* orow = reinterpret_cast<float4*>(xws + (size_t)node * HID);
#pragma unroll
        for (int j4 = 0; j4 < 4; ++j4)
            orow[j4] = make_float4(acc[j4 * 4 + 0] * dv, acc[j4 * 4 + 1] * dv,
                                   acc[j4 * 4 + 2] * dv, acc[j4 * 4 + 3] * dv);
    }
}

// Gather layer 1: 1 node/wave, j = lane&15, 4-way edge parallel (c = lane>>4).
// 4-deep unroll: 4 independent index loads then 4 independent gathers -> MLP 4.
__global__ __launch_bounds__(256) void k_gather1(const int* __restrict__ startA,
                                                 const int* __restrict__ cntA,
                                                 const int* __restrict__ esrc,
                                                 const float* __restrict__ xws,
                                                 const float* __restrict__ dinv,
                                                 const float* __restrict__ b1,
                                                 float* __restrict__ hout) {
    int wave = (blockIdx.x * 256 + threadIdx.x) >> 6;
    if (wave >= NN) return;
    int i = wave;
    int lane = threadIdx.x & 63;
    int j = lane & 15;
    int c = lane >> 4;                  // 0..3
    int st = startA[i], en = st + cntA[i];
    float s0 = 0.f, s1 = 0.f, s2 = 0.f, s3 = 0.f;
    int e = st + c;
    for (; e + 12 < en; e += 16) {      // 16 edges/iter wave-wide, 4 per c-group
        int a0 = esrc[e];
        int a1 = esrc[e + 4];
        int a2 = esrc[e + 8];
        int a3 = esrc[e + 12];
        s0 += xws[a0 * HID + j];
        s1 += xws[a1 * HID + j];
        s2 += xws[a2 * HID + j];
        s3 += xws[a3 * HID + j];
    }
    for (; e < en; e += 4) s0 += xws[esrc[e] * HID + j];
    float sum = (s0 + s1) + (s2 + s3);
    sum += __shfl_xor(sum, 16);
    sum += __shfl_xor(sum, 32);
    if (c == 0) {
        float v = b1[j] + dinv[i] * (sum + xws[i * HID + j]);
        hout[i * HID + j] = v > 0.f ? v : 0.f;
    }
}

// GEMM2: thread per (node, jo<32); W2 in LDS.
__global__ __launch_bounds__(256) void k_hw(const float* __restrict__ h,
                                            const float* __restrict__ W2,
                                            const float* __restrict__ dinv,
                                            float* __restrict__ hws) {
    __shared__ float w2[HID * NCLS];
    for (int t = threadIdx.x; t < HID * NCLS; t += 256) w2[t] = W2[t];
    __syncthreads();
    int t = blockIdx.x * blockDim.x + threadIdx.x;
    if (t >= NN * NCLS) return;
    int i = t >> 5, jo = t & 31;
    const float* hrow = h + i * HID;
    float acc = 0.f;
#pragma unroll
    for (int k = 0; k < HID; ++k) acc += hrow[k] * w2[k * NCLS + jo];
    hws[t] = acc * dinv[i];
}

// Gather layer 2: 1 node/wave, j = lane&31, 2-way edge parallel (c = lane>>5).
// 4-deep unroll -> MLP 4.
__global__ __launch_bounds__(256) void k_gather2(const int* __restrict__ startA,
                                                 const int* __restrict__ cntA,
                                                 const int* __restrict__ esrc,
                                                 const float* __restrict__ hws,
                                                 const float* __restrict__ dinv,
                                                 const float* __restrict__ b2,
                                                 float* __restrict__ out) {
    int wave = (blockIdx.x * 256 + threadIdx.x) >> 6;
    if (wave >= NN) return;
    int i = wave;
    int lane = threadIdx.x & 63;
    int j = lane & 31;
    int c = lane >> 5;                  // 0..1
    int st = startA[i], en = st + cntA[i];
    float s0 = 0.f, s1 = 0.f, s2 = 0.f, s3 = 0.f;
    int e = st + c;
    for (; e + 6 < en; e += 8) {        // 8 edges/iter wave-wide, 4 per c-group
        int a0 = esrc[e];
        int a1 = esrc[e + 2];
        int a2 = esrc[e + 4];
        int a3 = esrc[e + 6];
        s0 += hws[a0 * NCLS + j];
        s1 += hws[a1 * NCLS + j];
        s2 += hws[a2 * NCLS + j];
        s3 += hws[a3 * NCLS + j];
    }
    for (; e < en; e += 2) s0 += hws[esrc[e] * NCLS + j];
    float sum = (s0 + s1) + (s2 + s3);
    sum += __shfl_xor(sum, 32);
    if (c == 0)
        out[i * NCLS + j] = b2[j] + dinv[i] * (sum + hws[i * NCLS + j]);
}

extern "C" void kernel_launch(void* const* d_in, const int* in_sizes, int n_in,
                              void* d_out, int out_size, void* d_ws, size_t ws_size,
                              hipStream_t stream) {
    const float* x  = (const float*)d_in[0];
    const int* ei   = (const int*)d_in[1];      // [2][NE]
    const float* W1 = (const float*)d_in[2];
    const float* b1 = (const float*)d_in[3];
    const float* W2 = (const float*)d_in[4];
    const float* b2 = (const float*)d_in[5];

    const int* src = ei;
    const int* dst = ei + NE;

    int* wsi = (int*)d_ws;
    int*      bcnt  = wsi + OFF_BCNT;
    int*      bbase = wsi + OFF_BBASE;
    int*      bpos  = wsi + OFF_BPOS;
    int*      startA= wsi + OFF_START;
    int*      cntA  = wsi + OFF_CNT;
    float*    dinv  = (float*)(wsi + OFF_DINV);
    unsigned* ep    = (unsigned*)(wsi + OFF_EP);   // packed, then esrc
    float*    xws   = (float*)(wsi + OFF_XWS);
    float*    hws   = (float*)(wsi + OFF_HWS);

    float* outp = (float*)d_out;           // [NN*32]
    float* hout = outp + NN * NCLS;        // [NN*16]

    const int B = 256;

    hipLaunchKernelGGL(k_zeroB, dim3(1), dim3(512), 0, stream, bcnt);
    hipLaunchKernelGGL(k_bhist, dim3(512), dim3(B), 0, stream, dst, bcnt);
    hipLaunchKernelGGL(k_bscan, dim3(1), dim3(512), 0, stream, bcnt, bbase, bpos);
    hipLaunchKernelGGL(k_binA,  dim3((NE + 8191) / 8192), dim3(512), 0, stream, src, dst, bpos, ep);
    hipLaunchKernelGGL(k_binB,  dim3(NB), dim3(B), 0, stream, ep, bbase, bcnt, startA, cntA, dinv);
    hipLaunchKernelGGL(k_xw,    dim3((NN * 4 + B - 1) / B), dim3(B), 0, stream, x, W1, dinv, xws);
    hipLaunchKernelGGL(k_gather1, dim3((NN * 64 + B - 1) / B), dim3(B), 0, stream,
                       startA, cntA, (const int*)ep, xws, dinv, b1, hout);
    hipLaunchKernelGGL(k_hw,    dim3((NN * NCLS + B - 1) / B), dim3(B), 0, stream, hout, W2, dinv, hws);
    hipLaunchKernelGGL(k_gather2, dim3((NN * 64 + B - 1) / B), dim3(B), 0, stream,
                       startA, cntA, (const int*)ep, hws, dinv, b2, outp);
}